// Round 5
// baseline (970.290 us; speedup 1.0000x reference)
//
#include <hip/hip_runtime.h>
#include <hip/hip_bf16.h>

typedef _Float16 f16x8 __attribute__((ext_vector_type(8)));
typedef float f32x4 __attribute__((ext_vector_type(4)));

__device__ __forceinline__ float tanh_fast(float x) {
  float e = __expf(2.0f * x);
  return 1.0f - 2.0f * __builtin_amdgcn_rcpf(e + 1.0f);
}
__device__ __forceinline__ float sigmoid_fast(float x) {
  return __builtin_amdgcn_rcpf(1.0f + __expf(-x));
}

// ---------------- K0: all 4 weight transposes in one dispatch ----------------
__global__ __launch_bounds__(256) void transpose_all(
    const float* __restrict__ W1, const float* __restrict__ W2,
    const float* __restrict__ Wq1, const float* __restrict__ Wq2,
    _Float16* __restrict__ V1t, _Float16* __restrict__ V2t,
    _Float16* __restrict__ T1t, _Float16* __restrict__ T2t) {
  __shared__ float tile[32][33];
  int b = blockIdx.x;
  const float* in; _Float16* out; int R, C, rt, ct;
  if (b < 32) {                    // W1: 32 x (32x32)
    in = W1 + b * 1024; out = V1t + b * 1024; R = 32; C = 32; rt = 0; ct = 0;
  } else if (b < 32 + 1024) {      // W2: 32 x (1024x32)
    int i = b - 32; int z = i >> 5;
    in = W2 + (size_t)z * 32768; out = V2t + (size_t)z * 32768;
    R = 1024; C = 32; rt = i & 31; ct = 0;
  } else if (b < 32 + 1024 + 256) {  // Wq1: 1024x256
    int i = b - 1056; in = Wq1; out = T1t; R = 1024; C = 256; rt = i >> 3; ct = i & 7;
  } else {                         // Wq2: 256x128
    int i = b - 1312; in = Wq2; out = T2t; R = 256; C = 128; rt = i >> 2; ct = i & 3;
  }
  int r0 = rt * 32, c0 = ct * 32;
  int t = threadIdx.x;
  int cc = t & 31, rr8 = t >> 5;
#pragma unroll
  for (int p = 0; p < 4; ++p) {
    int r = rr8 + p * 8;
    tile[cc][r] = in[(size_t)(r0 + r) * C + c0 + cc];
  }
  __syncthreads();
  int rr = t & 31, cc8 = t >> 5;
#pragma unroll
  for (int p = 0; p < 4; ++p) {
    int c = cc8 + p * 8;
    out[(size_t)(c0 + c) * R + r0 + rr] = (_Float16)tile[c][rr];
  }
}

// ---------------- K1: ripple layer 1 ----------------
__global__ __launch_bounds__(256) void k1_ripple1(
    const float* __restrict__ state, const float* __restrict__ action,
    const _Float16* __restrict__ v1t, const float* __restrict__ b1,
    const float* __restrict__ g1, _Float16* __restrict__ x1, int gro) {
  __shared__ __align__(16) _Float16 As[128 * 40];
  int bn = blockIdx.x, bm = blockIdx.y;
  int t = threadIdx.x, w = t >> 6, l = t & 63, q = l >> 4, l15 = l & 15;
  int n0 = bn * 128, m0 = bm * 128;

  {  // stage sa tile [128][32] fp16 (concat state|action)
    int r = t >> 1, half = t & 1;
    size_t grow = (size_t)(gro + m0 + r);
    float v[16];
    if (half == 0) {
      const float4* sp = (const float4*)(state + grow * 24);
      ((float4*)v)[0] = sp[0]; ((float4*)v)[1] = sp[1];
      ((float4*)v)[2] = sp[2]; ((float4*)v)[3] = sp[3];
    } else {
      const float4* sp = (const float4*)(state + grow * 24 + 16);
      ((float4*)v)[0] = sp[0]; ((float4*)v)[1] = sp[1];
      const float4* ap = (const float4*)(action + grow * 8);
      ((float4*)v)[2] = ap[0]; ((float4*)v)[3] = ap[1];
    }
    f16x8 h0, h1;
#pragma unroll
    for (int j = 0; j < 8; ++j) { h0[j] = (_Float16)v[j]; h1[j] = (_Float16)v[8 + j]; }
    *(f16x8*)&As[r * 40 + half * 16] = h0;
    *(f16x8*)&As[r * 40 + half * 16 + 8] = h1;
  }
  __syncthreads();

  int wr = w >> 1, wc = w & 1;
  f16x8 af[4], bf[4];
#pragma unroll
  for (int mi = 0; mi < 4; ++mi)
    af[mi] = *(const f16x8*)&As[(wr * 64 + mi * 16 + l15) * 40 + q * 8];
#pragma unroll
  for (int ni = 0; ni < 4; ++ni)
    bf[ni] = *(const f16x8*)(v1t + (size_t)(n0 + wc * 64 + ni * 16 + l15) * 32 + q * 8);

  f32x4 acc[4][4] = {};
#pragma unroll
  for (int mi = 0; mi < 4; ++mi)
#pragma unroll
    for (int ni = 0; ni < 4; ++ni)
      acc[mi][ni] = __builtin_amdgcn_mfma_f32_16x16x32_f16(af[mi], bf[ni], acc[mi][ni], 0, 0, 0);

  // epilogue: pack via LDS, coalesced dwordx4 stores; 4 passes of 32 cols
  for (int ni = 0; ni < 4; ++ni) {
    __syncthreads();
    int col = n0 + wc * 64 + ni * 16 + l15;
    float sg = sigmoid_fast(g1[col >> 5]);
    float bias = b1[col];
    int cl = wc * 16 + l15;
#pragma unroll
    for (int mi = 0; mi < 4; ++mi)
#pragma unroll
      for (int r = 0; r < 4; ++r) {
        int rl = wr * 64 + mi * 16 + q * 4 + r;
        As[rl * 40 + cl] = (_Float16)(tanh_fast(acc[mi][ni][r] + bias) * sg);
      }
    __syncthreads();
#pragma unroll
    for (int i = 0; i < 2; ++i) {
      int c = t + i * 256;
      int row = c >> 2, sub = c & 3;
      int colg = n0 + (sub >> 1) * 64 + ni * 16 + (sub & 1) * 8;
      *(float4*)(x1 + (size_t)(m0 + row) * 1024 + colg) = *(const float4*)&As[row * 40 + sub * 8];
    }
  }
}

// ---------------- K2: ripple layer 2 (the big GEMM) ----------------
// Pipelined K-loop, NO global_load_lds: A staged global->VGPR->ds_write into a
// double buffer (one barrier/iter, barrier waits lgkmcnt only), B fragments
// loaded directly from L2-resident V2t into MFMA registers (vmcnt waits are
// fine-grained, no drain-at-barrier). 128x128 tile, 2x2 waves of 64x64.
__global__ __launch_bounds__(256, 3) void k2_ripple2(
    const _Float16* __restrict__ x1, const _Float16* __restrict__ v2t,
    const float* __restrict__ b2, const float* __restrict__ g2,
    _Float16* __restrict__ x2, int nbm) {
  __shared__ __align__(16) _Float16 SMEM[9216];   // dbuf 2x8 KB; epilogue 18 KB
  int g = blockIdx.x;
  int bn, bm;
  if ((nbm & 7) == 0) {
    int x = g & 7, j = g >> 3;
    bn = j & 7; bm = x + 8 * (j >> 3);
  } else { bn = g & 7; bm = g >> 3; }
  int t = threadIdx.x, w = t >> 6, l = t & 63, q = l >> 4, l15 = l & 15;
  int n0 = bn * 128, m0 = bm * 128;
  int wr = w >> 1, wc = w & 1;
  f32x4 acc[4][4] = {};

  // A staging addresses (swizzled parts; thread t owns chunks t, t+256)
  int c0 = t, c1 = t + 256;
  const _Float16* aS0 = x1 + (size_t)(m0 + (c0 >> 2)) * 1024 + ((c0 & 3) ^ ((c0 >> 3) & 3)) * 8;
  const _Float16* aS1 = x1 + (size_t)(m0 + (c1 >> 2)) * 1024 + ((c1 & 3) ^ ((c1 >> 3) & 3)) * 8;
  // B fragment pointers (direct global)
  const _Float16* bP[4];
#pragma unroll
  for (int ni = 0; ni < 4; ++ni)
    bP[ni] = v2t + (size_t)(n0 + wc * 64 + ni * 16 + l15) * 1024 + q * 8;
  int qs = q ^ ((l15 >> 1) & 3);

  f16x8 ra0 = *(const f16x8*)aS0;
  f16x8 ra1 = *(const f16x8*)aS1;

  for (int kt = 0; kt < 32; ++kt) {
    _Float16* buf = SMEM + (kt & 1) * 4096;
    *(f16x8*)(buf + c0 * 8) = ra0;
    *(f16x8*)(buf + c1 * 8) = ra1;
    __syncthreads();
    if (kt < 31) {
      ra0 = *(const f16x8*)(aS0 + (kt + 1) * 32);
      ra1 = *(const f16x8*)(aS1 + (kt + 1) * 32);
    }
    f16x8 bf[4];
#pragma unroll
    for (int ni = 0; ni < 4; ++ni)
      bf[ni] = *(const f16x8*)(bP[ni] + kt * 32);
    f16x8 af[4];
#pragma unroll
    for (int mi = 0; mi < 4; ++mi)
      af[mi] = *(const f16x8*)&buf[(wr * 64 + mi * 16 + l15) * 32 + qs * 8];
#pragma unroll
    for (int mi = 0; mi < 4; ++mi)
#pragma unroll
      for (int ni = 0; ni < 4; ++ni)
        acc[mi][ni] = __builtin_amdgcn_mfma_f32_16x16x32_f16(af[mi], bf[ni], acc[mi][ni], 0, 0, 0);
  }

  // epilogue: gate+tanh, pack 128x64 per pass (stride 72), dwordx4 stores
  for (int pass = 0; pass < 2; ++pass) {
    __syncthreads();
#pragma unroll
    for (int ni2 = 0; ni2 < 2; ++ni2) {
      int ni = pass * 2 + ni2;
      int col = n0 + wc * 64 + ni * 16 + l15;
      float sg = sigmoid_fast(g2[col >> 5]);
      float bias = b2[col];
      int cl = wc * 32 + ni2 * 16 + l15;
#pragma unroll
      for (int mi = 0; mi < 4; ++mi)
#pragma unroll
        for (int r = 0; r < 4; ++r) {
          int rl = wr * 64 + mi * 16 + q * 4 + r;
          SMEM[rl * 72 + cl] = (_Float16)(tanh_fast(acc[mi][ni][r] + bias) * sg);
        }
    }
    __syncthreads();
#pragma unroll
    for (int i = 0; i < 4; ++i) {
      int c = t + i * 256;
      int row = c >> 3, sub = c & 7;
      int colg = n0 + (sub >> 2) * 64 + (pass * 2 + ((sub >> 1) & 1)) * 16 + (sub & 1) * 8;
      *(float4*)(x2 + (size_t)(m0 + row) * 1024 + colg) = *(const float4*)&SMEM[row * 72 + sub * 8];
    }
  }
}

// ---------------- K3: fused q-network head ----------------
// GEMM3 uses the same pipelined structure: A dbuf via VGPR roundtrip, B (T1t,
// L2-resident) direct to registers. M=128, N=256, 512 threads (2x4 waves).
__global__ __launch_bounds__(512, 4) void k3_head(
    const _Float16* __restrict__ x2, const _Float16* __restrict__ t1t,
    const _Float16* __restrict__ t2t,
    const float* __restrict__ bq1, const float* __restrict__ ln1g, const float* __restrict__ ln1b,
    const float* __restrict__ bq2, const float* __restrict__ ln2g, const float* __restrict__ ln2b,
    const float* __restrict__ wq3, const float* __restrict__ bq3,
    float* __restrict__ out) {
  __shared__ __align__(16) _Float16 y1h[128 * 264];   // 66 KB; front 16 KB = A dbuf
  __shared__ float redA[128 * 4], redB[128 * 4];
  __shared__ float meanv[128], rstdv[128];
  int bm = blockIdx.x;
  int t = threadIdx.x, w = t >> 6, l = t & 63, q = l >> 4, l15 = l & 15;
  int wr = w >> 2, wc = w & 3;   // 2 x 4 wave grid
  int m0 = bm * 128;
  int qs = q ^ ((l15 >> 1) & 3);

  // ---- GEMM3: [128 x 1024] @ [1024 x 256]
  f32x4 acc[4][4] = {};
  const _Float16* aS = x2 + (size_t)(m0 + (t >> 2)) * 1024 + ((t & 3) ^ ((t >> 3) & 3)) * 8;
  const _Float16* bP[4];
#pragma unroll
  for (int ni = 0; ni < 4; ++ni)
    bP[ni] = t1t + (size_t)(wc * 64 + ni * 16 + l15) * 1024 + q * 8;

  f16x8 ra = *(const f16x8*)aS;

  for (int kt = 0; kt < 32; ++kt) {
    _Float16* buf = y1h + (kt & 1) * 4096;
    *(f16x8*)(buf + t * 8) = ra;
    __syncthreads();
    if (kt < 31) ra = *(const f16x8*)(aS + (kt + 1) * 32);
    f16x8 bf[4];
#pragma unroll
    for (int ni = 0; ni < 4; ++ni)
      bf[ni] = *(const f16x8*)(bP[ni] + kt * 32);
    f16x8 af[4];
#pragma unroll
    for (int mi = 0; mi < 4; ++mi)
      af[mi] = *(const f16x8*)&buf[(wr * 64 + mi * 16 + l15) * 32 + qs * 8];
#pragma unroll
    for (int mi = 0; mi < 4; ++mi)
#pragma unroll
      for (int ni = 0; ni < 4; ++ni)
        acc[mi][ni] = __builtin_amdgcn_mfma_f32_16x16x32_f16(af[mi], bf[ni], acc[mi][ni], 0, 0, 0);
    __syncthreads();   // protect buf from next iter's overwrite vs stragglers
  }

  // bias + row-sum/sumsq over 256 cols
#pragma unroll
  for (int ni = 0; ni < 4; ++ni) {
    int col = wc * 64 + ni * 16 + l15;
    float b = bq1[col];
#pragma unroll
    for (int mi = 0; mi < 4; ++mi)
#pragma unroll
      for (int r = 0; r < 4; ++r) acc[mi][ni][r] += b;
  }
#pragma unroll
  for (int mi = 0; mi < 4; ++mi)
#pragma unroll
    for (int r = 0; r < 4; ++r) {
      int row = wr * 64 + mi * 16 + q * 4 + r;
      float s = 0.f, sq = 0.f;
#pragma unroll
      for (int ni = 0; ni < 4; ++ni) { float v = acc[mi][ni][r]; s += v; sq += v * v; }
#pragma unroll
      for (int off = 1; off < 16; off <<= 1) { s += __shfl_xor(s, off); sq += __shfl_xor(sq, off); }
      if (l15 == 0) { redA[row * 4 + wc] = s; redB[row * 4 + wc] = sq; }
    }
  __syncthreads();
  if (t < 128) {
    float s  = redA[t * 4] + redA[t * 4 + 1] + redA[t * 4 + 2] + redA[t * 4 + 3];
    float sq = redB[t * 4] + redB[t * 4 + 1] + redB[t * 4 + 2] + redB[t * 4 + 3];
    float mean = s * (1.0f / 256.0f);
    float var = sq * (1.0f / 256.0f) - mean * mean;
    meanv[t] = mean; rstdv[t] = rsqrtf(var + 1e-5f);
  }
  __syncthreads();
  // LN + relu -> y1h (overwrites dbuf region; all reads done)
#pragma unroll
  for (int mi = 0; mi < 4; ++mi)
#pragma unroll
    for (int ni = 0; ni < 4; ++ni)
#pragma unroll
      for (int r = 0; r < 4; ++r) {
        int row = wr * 64 + mi * 16 + q * 4 + r;
        int col = wc * 64 + ni * 16 + l15;
        float y = (acc[mi][ni][r] - meanv[row]) * rstdv[row] * ln1g[col] + ln1b[col];
        y = fmaxf(y, 0.f);
        y1h[row * 264 + col] = (_Float16)y;
      }
  __syncthreads();

  // ---- GEMM4: [128 x 256] @ [256 x 128]; waves 2(row x64) x 4(col x32)
  f32x4 a2[4][2] = {};
  for (int kt = 0; kt < 8; ++kt) {
    f16x8 af2[4];
#pragma unroll
    for (int mi = 0; mi < 4; ++mi)
      af2[mi] = *(const f16x8*)&y1h[(wr * 64 + mi * 16 + l15) * 264 + kt * 32 + q * 8];
#pragma unroll
    for (int ni = 0; ni < 2; ++ni) {
      f16x8 bf = *(const f16x8*)(t2t + (size_t)(wc * 32 + ni * 16 + l15) * 256 + kt * 32 + q * 8);
#pragma unroll
      for (int mi = 0; mi < 4; ++mi)
        a2[mi][ni] = __builtin_amdgcn_mfma_f32_16x16x32_f16(af2[mi], bf, a2[mi][ni], 0, 0, 0);
    }
  }
#pragma unroll
  for (int ni = 0; ni < 2; ++ni) {
    int col = wc * 32 + ni * 16 + l15;
    float b = bq2[col];
#pragma unroll
    for (int mi = 0; mi < 4; ++mi)
#pragma unroll
      for (int r = 0; r < 4; ++r) a2[mi][ni][r] += b;
  }
  __syncthreads();   // redA/redB reuse
#pragma unroll
  for (int mi = 0; mi < 4; ++mi)
#pragma unroll
    for (int r = 0; r < 4; ++r) {
      int row = wr * 64 + mi * 16 + q * 4 + r;
      float s = 0.f, sq = 0.f;
#pragma unroll
      for (int ni = 0; ni < 2; ++ni) { float v = a2[mi][ni][r]; s += v; sq += v * v; }
#pragma unroll
      for (int off = 1; off < 16; off <<= 1) { s += __shfl_xor(s, off); sq += __shfl_xor(sq, off); }
      if (l15 == 0) { redA[row * 4 + wc] = s; redB[row * 4 + wc] = sq; }
    }
  __syncthreads();
  if (t < 128) {
    float s  = redA[t * 4] + redA[t * 4 + 1] + redA[t * 4 + 2] + redA[t * 4 + 3];
    float sq = redB[t * 4] + redB[t * 4 + 1] + redB[t * 4 + 2] + redB[t * 4 + 3];
    float mean = s * (1.0f / 128.0f);
    float var = sq * (1.0f / 128.0f) - mean * mean;
    meanv[t] = mean; rstdv[t] = rsqrtf(var + 1e-5f);
  }
  __syncthreads();
  // LN + relu + dot(wq3)
#pragma unroll
  for (int mi = 0; mi < 4; ++mi)
#pragma unroll
    for (int r = 0; r < 4; ++r) {
      int row = wr * 64 + mi * 16 + q * 4 + r;
      float pr = 0.f;
#pragma unroll
      for (int ni = 0; ni < 2; ++ni) {
        int col = wc * 32 + ni * 16 + l15;
        float y = (a2[mi][ni][r] - meanv[row]) * rstdv[row] * ln2g[col] + ln2b[col];
        y = fmaxf(y, 0.f);
        pr += y * wq3[col];
      }
#pragma unroll
      for (int off = 1; off < 16; off <<= 1) pr += __shfl_xor(pr, off);
      if (l15 == 0) redA[row * 4 + wc] = pr;
    }
  __syncthreads();
  if (t < 128)
    out[m0 + t] = redA[t * 4] + redA[t * 4 + 1] + redA[t * 4 + 2] + redA[t * 4 + 3] + bq3[0];
}

// ---------------- launcher ----------------
extern "C" void kernel_launch(void* const* d_in, const int* in_sizes, int n_in,
                              void* d_out, int out_size, void* d_ws, size_t ws_size,
                              hipStream_t stream) {
  const float* state  = (const float*)d_in[0];
  const float* action = (const float*)d_in[1];
  const float* W1  = (const float*)d_in[2];
  const float* b1  = (const float*)d_in[3];
  const float* g1  = (const float*)d_in[4];
  const float* W2  = (const float*)d_in[5];
  const float* b2  = (const float*)d_in[6];
  const float* g2  = (const float*)d_in[7];
  const float* Wq1 = (const float*)d_in[8];
  const float* bq1 = (const float*)d_in[9];
  const float* ln1g = (const float*)d_in[10];
  const float* ln1b = (const float*)d_in[11];
  const float* Wq2 = (const float*)d_in[12];
  const float* bq2 = (const float*)d_in[13];
  const float* ln2g = (const float*)d_in[14];
  const float* ln2b = (const float*)d_in[15];
  const float* Wq3 = (const float*)d_in[16];
  const float* bq3 = (const float*)d_in[17];
  int B = in_sizes[0] / 24;

  char* ws = (char*)d_ws;
  _Float16* V1t = (_Float16*)(ws);
  _Float16* V2t = (_Float16*)(ws + 65536);
  _Float16* T1t = (_Float16*)(ws + 65536 + 2097152);
  _Float16* T2t = (_Float16*)(ws + 65536 + 2097152 + 524288);
  size_t woff = (65536 + 2097152 + 524288 + 65536 + 4095) & ~(size_t)4095;

  size_t avail = ws_size > woff ? ws_size - woff : 0;
  int S, G;
  if (avail >= (size_t)32768 * 2048 * 3) {
    S = 32768; G = 2;
  } else {
    long rows = (long)(avail / 4096);
    if (rows > 32768) rows = 32768;
    rows &= ~127L;
    if (rows < 128) rows = 128;
    S = (int)rows; G = 1;
  }
  _Float16* x1 = (_Float16*)(ws + woff);
  _Float16* x2 = x1 + (size_t)S * 1024;

  transpose_all<<<1344, 256, 0, stream>>>(W1, W2, Wq1, Wq2, V1t, V2t, T1t, T2t);

  int nsl = (B + S - 1) / S;
  for (int i = 0; i < nsl; ++i) {
    int r0 = i * S;
    int Sc = S < (B - r0) ? S : (B - r0);
    int nbm = Sc / 128;
    k1_ripple1<<<dim3(8, nbm), 256, 0, stream>>>(state, action, V1t, b1, g1, x1, r0);
    k2_ripple2<<<dim3(8 * nbm), 256, 0, stream>>>(x1, V2t, b2, g2,
                                                  x2 + (size_t)(i % G) * S * 1024, nbm);
    if (i % G == G - 1 || i == nsl - 1) {
      int gstart = (i - i % G) * S;
      int nrows = r0 + Sc - gstart;
      k3_head<<<dim3(nrows / 128), 512, 0, stream>>>(x2, T1t, T2t, bq1, ln1g, ln1b,
                                                     bq2, ln2g, ln2b, Wq3, bq3,
                                                     (float*)d_out + gstart);
    }
  }
}

// Round 6
// 709.185 us; speedup vs baseline: 1.3682x; 1.3682x over previous
//
#include <hip/hip_runtime.h>
#include <hip/hip_bf16.h>

typedef _Float16 f16x8 __attribute__((ext_vector_type(8)));
typedef _Float16 f16x4 __attribute__((ext_vector_type(4)));
typedef float f32x4 __attribute__((ext_vector_type(4)));

__device__ __forceinline__ float tanh_fast(float x) {
  float e = __expf(2.0f * x);
  return 1.0f - 2.0f * __builtin_amdgcn_rcpf(e + 1.0f);
}
__device__ __forceinline__ float sigmoid_fast(float x) {
  return __builtin_amdgcn_rcpf(1.0f + __expf(-x));
}

// ---------------- K0: weight prep ----------------
// V1t: plain transpose (K=32 -> already wave-coalesced as [col][k]).
// V2p/T1p/T2p: fragment-major pack: for (n-tile nt of 16 cols, k-chunk kt of 32),
// lane l, j: out[(tile*64+l)*8+j] = in[k=kt*32+(l>>4)*8+j][col=nt*16+(l&15)],
// tile = nt*KT + kt. A wave's B-fragment load is then 1 KB contiguous.
__global__ __launch_bounds__(256) void prep_weights(
    const float* __restrict__ W1, const float* __restrict__ W2,
    const float* __restrict__ Wq1, const float* __restrict__ Wq2,
    _Float16* __restrict__ V1t, _Float16* __restrict__ V2p,
    _Float16* __restrict__ T1p, _Float16* __restrict__ T2p) {
  __shared__ float S[32 * 33];
  int b = blockIdx.x, t = threadIdx.x;
  if (b < 2624) {
    const float* in; _Float16* out; int N, nc0, tile;
    if (b < 2048) {        // W2 [32][1024][32]: h, ntl, kt
      int h = b >> 6, rem = b & 63, ntl = rem >> 5, kt = rem & 31;
      in = W2 + (size_t)h * 32768 + (size_t)kt * 32 * 32;
      N = 32; nc0 = ntl * 16;
      out = V2p; tile = (h * 2 + ntl) * 32 + kt;
    } else if (b < 2560) { // Wq1 [1024][256]
      int i = b - 2048, nt = i >> 5, kt = i & 31;
      in = Wq1 + (size_t)kt * 32 * 256; N = 256; nc0 = nt * 16;
      out = T1p; tile = nt * 32 + kt;
    } else {               // Wq2 [256][128]
      int i = b - 2560, nt = i >> 3, kt = i & 7;
      in = Wq2 + (size_t)kt * 32 * 128; N = 128; nc0 = nt * 16;
      out = T2p; tile = nt * 8 + kt;
    }
    if (t < 128) {
      int r = t >> 2, c4 = (t & 3) * 4;
      const float4 v = *(const float4*)(in + (size_t)r * N + nc0 + c4);
      S[r * 17 + c4 + 0] = v.x; S[r * 17 + c4 + 1] = v.y;
      S[r * 17 + c4 + 2] = v.z; S[r * 17 + c4 + 3] = v.w;
    }
    __syncthreads();
    if (t < 128) {
      int w2 = t >> 6, l = t & 63, q = l >> 4, l15 = l & 15;
      f16x4 o;
#pragma unroll
      for (int jj = 0; jj < 4; ++jj)
        o[jj] = (_Float16)S[(q * 8 + w2 * 4 + jj) * 17 + l15];
      *(f16x4*)(out + (size_t)tile * 512 + l * 8 + w2 * 4) = o;
    }
  } else {                 // W1: 32 slabs of 32x32 transpose
    int z = b - 2624;
    const float* in = W1 + z * 1024;
    _Float16* out = V1t + z * 1024;
    int cc = t & 31, rr8 = t >> 5;
#pragma unroll
    for (int p = 0; p < 4; ++p) {
      int r = rr8 + p * 8;
      S[cc * 33 + r] = in[r * 32 + cc];
    }
    __syncthreads();
    int rr = t & 31, cc8 = t >> 5;
#pragma unroll
    for (int p = 0; p < 4; ++p) {
      int c = cc8 + p * 8;
      out[c * 32 + rr] = (_Float16)S[c * 33 + rr];
    }
  }
}

// ---------------- K1: ripple layer 1 ----------------
__global__ __launch_bounds__(256) void k1_ripple1(
    const float* __restrict__ state, const float* __restrict__ action,
    const _Float16* __restrict__ v1t, const float* __restrict__ b1,
    const float* __restrict__ g1, _Float16* __restrict__ x1, int gro) {
  __shared__ __align__(16) _Float16 As[128 * 40];
  int bn = blockIdx.x, bm = blockIdx.y;
  int t = threadIdx.x, w = t >> 6, l = t & 63, q = l >> 4, l15 = l & 15;
  int n0 = bn * 128, m0 = bm * 128;

  {  // stage sa tile [128][32] fp16 (concat state|action)
    int r = t >> 1, half = t & 1;
    size_t grow = (size_t)(gro + m0 + r);
    float v[16];
    if (half == 0) {
      const float4* sp = (const float4*)(state + grow * 24);
      ((float4*)v)[0] = sp[0]; ((float4*)v)[1] = sp[1];
      ((float4*)v)[2] = sp[2]; ((float4*)v)[3] = sp[3];
    } else {
      const float4* sp = (const float4*)(state + grow * 24 + 16);
      ((float4*)v)[0] = sp[0]; ((float4*)v)[1] = sp[1];
      const float4* ap = (const float4*)(action + grow * 8);
      ((float4*)v)[2] = ap[0]; ((float4*)v)[3] = ap[1];
    }
    f16x8 h0, h1;
#pragma unroll
    for (int j = 0; j < 8; ++j) { h0[j] = (_Float16)v[j]; h1[j] = (_Float16)v[8 + j]; }
    *(f16x8*)&As[r * 40 + half * 16] = h0;
    *(f16x8*)&As[r * 40 + half * 16 + 8] = h1;
  }
  __syncthreads();

  int wr = w >> 1, wc = w & 1;
  f16x8 af[4], bf[4];
#pragma unroll
  for (int mi = 0; mi < 4; ++mi)
    af[mi] = *(const f16x8*)&As[(wr * 64 + mi * 16 + l15) * 40 + q * 8];
#pragma unroll
  for (int ni = 0; ni < 4; ++ni)
    bf[ni] = *(const f16x8*)(v1t + (size_t)(n0 + wc * 64 + ni * 16 + l15) * 32 + q * 8);

  f32x4 acc[4][4] = {};
#pragma unroll
  for (int mi = 0; mi < 4; ++mi)
#pragma unroll
    for (int ni = 0; ni < 4; ++ni)
      acc[mi][ni] = __builtin_amdgcn_mfma_f32_16x16x32_f16(af[mi], bf[ni], acc[mi][ni], 0, 0, 0);

  // epilogue: pack via LDS, coalesced dwordx4 stores; 4 passes of 32 cols
  for (int ni = 0; ni < 4; ++ni) {
    __syncthreads();
    int col = n0 + wc * 64 + ni * 16 + l15;
    float sg = sigmoid_fast(g1[col >> 5]);
    float bias = b1[col];
    int cl = wc * 16 + l15;
#pragma unroll
    for (int mi = 0; mi < 4; ++mi)
#pragma unroll
      for (int r = 0; r < 4; ++r) {
        int rl = wr * 64 + mi * 16 + q * 4 + r;
        As[rl * 40 + cl] = (_Float16)(tanh_fast(acc[mi][ni][r] + bias) * sg);
      }
    __syncthreads();
#pragma unroll
    for (int i = 0; i < 2; ++i) {
      int c = t + i * 256;
      int row = c >> 2, sub = c & 3;
      int colg = n0 + (sub >> 1) * 64 + ni * 16 + (sub & 1) * 8;
      *(float4*)(x1 + (size_t)(m0 + row) * 1024 + colg) = *(const float4*)&As[row * 40 + sub * 8];
    }
  }
}

// ---------------- K2: ripple layer 2 (the big GEMM) ----------------
// Drain-free pipelined K-loop: A via VGPR->ds_write parity dbuf (barrier waits
// lgkm only); B fragments direct from fragment-major V2p (1 KB coalesced wave
// loads), prefetched one kt ahead. 128x128 tile, 2x2 waves of 64x64.
__global__ __launch_bounds__(256, 3) void k2_ripple2(
    const _Float16* __restrict__ x1, const _Float16* __restrict__ v2p,
    const float* __restrict__ b2, const float* __restrict__ g2,
    _Float16* __restrict__ x2, int nbm) {
  __shared__ __align__(16) _Float16 SMEM[9216];   // dbuf 2x8KB; epilogue 18KB
  int g = blockIdx.x;
  int bn, bm;
  if ((nbm & 7) == 0) {
    int x = g & 7, j = g >> 3;
    bn = j & 7; bm = x + 8 * (j >> 3);
  } else { bn = g & 7; bm = g >> 3; }
  int t = threadIdx.x, w = t >> 6, l = t & 63, q = l >> 4, l15 = l & 15;
  int n0 = bn * 128, m0 = bm * 128;
  int wr = w >> 1, wc = w & 1;
  f32x4 acc[4][4] = {};

  int c0 = t, c1 = t + 256;
  const _Float16* aS0 = x1 + (size_t)(m0 + (c0 >> 2)) * 1024 + ((c0 & 3) ^ ((c0 >> 3) & 3)) * 8;
  const _Float16* aS1 = x1 + (size_t)(m0 + (c1 >> 2)) * 1024 + ((c1 & 3) ^ ((c1 >> 3) & 3)) * 8;
  const _Float16* bP[4];
#pragma unroll
  for (int ni = 0; ni < 4; ++ni)
    bP[ni] = v2p + (size_t)(bn * 8 + wc * 4 + ni) * 16384 + l * 8;
  int qs = q ^ ((l15 >> 1) & 3);

  f16x8 ra0 = *(const f16x8*)aS0;
  f16x8 ra1 = *(const f16x8*)aS1;
  f16x8 bc[4], bnx[4];
#pragma unroll
  for (int ni = 0; ni < 4; ++ni) bc[ni] = *(const f16x8*)bP[ni];

#pragma unroll 2
  for (int kt = 0; kt < 32; ++kt) {
    _Float16* buf = SMEM + (kt & 1) * 4096;
    *(f16x8*)(buf + c0 * 8) = ra0;
    *(f16x8*)(buf + c1 * 8) = ra1;
    if (kt < 31) {
      ra0 = *(const f16x8*)(aS0 + (kt + 1) * 32);
      ra1 = *(const f16x8*)(aS1 + (kt + 1) * 32);
#pragma unroll
      for (int ni = 0; ni < 4; ++ni)
        bnx[ni] = *(const f16x8*)(bP[ni] + (kt + 1) * 512);
    }
    __syncthreads();
    f16x8 af[4];
#pragma unroll
    for (int mi = 0; mi < 4; ++mi)
      af[mi] = *(const f16x8*)&buf[(wr * 64 + mi * 16 + l15) * 32 + qs * 8];
#pragma unroll
    for (int mi = 0; mi < 4; ++mi)
#pragma unroll
      for (int ni = 0; ni < 4; ++ni)
        acc[mi][ni] = __builtin_amdgcn_mfma_f32_16x16x32_f16(af[mi], bc[ni], acc[mi][ni], 0, 0, 0);
#pragma unroll
    for (int ni = 0; ni < 4; ++ni) bc[ni] = bnx[ni];
  }

  // epilogue: gate+tanh, pack 128x64 per pass (stride 72), dwordx4 stores
  for (int pass = 0; pass < 2; ++pass) {
    __syncthreads();
#pragma unroll
    for (int ni2 = 0; ni2 < 2; ++ni2) {
      int ni = pass * 2 + ni2;
      int col = n0 + wc * 64 + ni * 16 + l15;
      float sg = sigmoid_fast(g2[col >> 5]);
      float bias = b2[col];
      int cl = wc * 32 + ni2 * 16 + l15;
#pragma unroll
      for (int mi = 0; mi < 4; ++mi)
#pragma unroll
        for (int r = 0; r < 4; ++r) {
          int rl = wr * 64 + mi * 16 + q * 4 + r;
          SMEM[rl * 72 + cl] = (_Float16)(tanh_fast(acc[mi][ni][r] + bias) * sg);
        }
    }
    __syncthreads();
#pragma unroll
    for (int i = 0; i < 4; ++i) {
      int c = t + i * 256;
      int row = c >> 3, sub = c & 7;
      int colg = n0 + (sub >> 2) * 64 + (pass * 2 + ((sub >> 1) & 1)) * 16 + (sub & 1) * 8;
      *(float4*)(x2 + (size_t)(m0 + row) * 1024 + colg) = *(const float4*)&SMEM[row * 72 + sub * 8];
    }
  }
}

// ---------------- K3: fused q-network head ----------------
// GEMM3: same drain-free structure (A dbuf + fragment-major T1p direct B).
// GEMM4: fragment-major T2p direct B. M=128, N=256, 512 threads (2x4 waves).
__global__ __launch_bounds__(512, 4) void k3_head(
    const _Float16* __restrict__ x2, const _Float16* __restrict__ t1p,
    const _Float16* __restrict__ t2p,
    const float* __restrict__ bq1, const float* __restrict__ ln1g, const float* __restrict__ ln1b,
    const float* __restrict__ bq2, const float* __restrict__ ln2g, const float* __restrict__ ln2b,
    const float* __restrict__ wq3, const float* __restrict__ bq3,
    float* __restrict__ out) {
  __shared__ __align__(16) _Float16 y1h[128 * 264];   // 66 KB; front 16 KB = A dbuf
  __shared__ float redA[128 * 4], redB[128 * 4];
  __shared__ float meanv[128], rstdv[128];
  int bm = blockIdx.x;
  int t = threadIdx.x, w = t >> 6, l = t & 63, q = l >> 4, l15 = l & 15;
  int wr = w >> 2, wc = w & 3;   // 2 x 4 wave grid
  int m0 = bm * 128;
  int qs = q ^ ((l15 >> 1) & 3);

  // ---- GEMM3: [128 x 1024] @ [1024 x 256]
  f32x4 acc[4][4] = {};
  const _Float16* aS = x2 + (size_t)(m0 + (t >> 2)) * 1024 + ((t & 3) ^ ((t >> 3) & 3)) * 8;
  const _Float16* bP[4];
#pragma unroll
  for (int ni = 0; ni < 4; ++ni)
    bP[ni] = t1p + (size_t)(wc * 4 + ni) * 16384 + l * 8;

  f16x8 ra = *(const f16x8*)aS;
  f16x8 bc[4], bnx[4];
#pragma unroll
  for (int ni = 0; ni < 4; ++ni) bc[ni] = *(const f16x8*)bP[ni];

#pragma unroll 2
  for (int kt = 0; kt < 32; ++kt) {
    _Float16* buf = y1h + (kt & 1) * 4096;
    *(f16x8*)(buf + t * 8) = ra;
    if (kt < 31) {
      ra = *(const f16x8*)(aS + (kt + 1) * 32);
#pragma unroll
      for (int ni = 0; ni < 4; ++ni)
        bnx[ni] = *(const f16x8*)(bP[ni] + (kt + 1) * 512);
    }
    __syncthreads();
    f16x8 af[4];
#pragma unroll
    for (int mi = 0; mi < 4; ++mi)
      af[mi] = *(const f16x8*)&buf[(wr * 64 + mi * 16 + l15) * 32 + qs * 8];
#pragma unroll
    for (int mi = 0; mi < 4; ++mi)
#pragma unroll
      for (int ni = 0; ni < 4; ++ni)
        acc[mi][ni] = __builtin_amdgcn_mfma_f32_16x16x32_f16(af[mi], bc[ni], acc[mi][ni], 0, 0, 0);
#pragma unroll
    for (int ni = 0; ni < 4; ++ni) bc[ni] = bnx[ni];
  }

  // bias + row-sum/sumsq over 256 cols
#pragma unroll
  for (int ni = 0; ni < 4; ++ni) {
    int col = wc * 64 + ni * 16 + l15;
    float b = bq1[col];
#pragma unroll
    for (int mi = 0; mi < 4; ++mi)
#pragma unroll
      for (int r = 0; r < 4; ++r) acc[mi][ni][r] += b;
  }
#pragma unroll
  for (int mi = 0; mi < 4; ++mi)
#pragma unroll
    for (int r = 0; r < 4; ++r) {
      int row = wr * 64 + mi * 16 + q * 4 + r;
      float s = 0.f, sq = 0.f;
#pragma unroll
      for (int ni = 0; ni < 4; ++ni) { float v = acc[mi][ni][r]; s += v; sq += v * v; }
#pragma unroll
      for (int off = 1; off < 16; off <<= 1) { s += __shfl_xor(s, off); sq += __shfl_xor(sq, off); }
      if (l15 == 0) { redA[row * 4 + wc] = s; redB[row * 4 + wc] = sq; }
    }
  __syncthreads();
  if (t < 128) {
    float s  = redA[t * 4] + redA[t * 4 + 1] + redA[t * 4 + 2] + redA[t * 4 + 3];
    float sq = redB[t * 4] + redB[t * 4 + 1] + redB[t * 4 + 2] + redB[t * 4 + 3];
    float mean = s * (1.0f / 256.0f);
    float var = sq * (1.0f / 256.0f) - mean * mean;
    meanv[t] = mean; rstdv[t] = rsqrtf(var + 1e-5f);
  }
  __syncthreads();
  // LN + relu -> y1h (overwrites dbuf region; all reads done)
#pragma unroll
  for (int mi = 0; mi < 4; ++mi)
#pragma unroll
    for (int ni = 0; ni < 4; ++ni)
#pragma unroll
      for (int r = 0; r < 4; ++r) {
        int row = wr * 64 + mi * 16 + q * 4 + r;
        int col = wc * 64 + ni * 16 + l15;
        float y = (acc[mi][ni][r] - meanv[row]) * rstdv[row] * ln1g[col] + ln1b[col];
        y = fmaxf(y, 0.f);
        y1h[row * 264 + col] = (_Float16)y;
      }
  __syncthreads();

  // ---- GEMM4: [128 x 256] @ [256 x 128]; waves 2(row x64) x 4(col x32)
  f32x4 a2[4][2] = {};
  for (int kt = 0; kt < 8; ++kt) {
    f16x8 af2[4];
#pragma unroll
    for (int mi = 0; mi < 4; ++mi)
      af2[mi] = *(const f16x8*)&y1h[(wr * 64 + mi * 16 + l15) * 264 + kt * 32 + q * 8];
#pragma unroll
    for (int ni = 0; ni < 2; ++ni) {
      f16x8 bf = *(const f16x8*)(t2p + (size_t)(wc * 2 + ni) * 4096 + kt * 512 + l * 8);
#pragma unroll
      for (int mi = 0; mi < 4; ++mi)
        a2[mi][ni] = __builtin_amdgcn_mfma_f32_16x16x32_f16(af2[mi], bf, a2[mi][ni], 0, 0, 0);
    }
  }
#pragma unroll
  for (int ni = 0; ni < 2; ++ni) {
    int col = wc * 32 + ni * 16 + l15;
    float b = bq2[col];
#pragma unroll
    for (int mi = 0; mi < 4; ++mi)
#pragma unroll
      for (int r = 0; r < 4; ++r) a2[mi][ni][r] += b;
  }
  __syncthreads();   // redA/redB reuse
#pragma unroll
  for (int mi = 0; mi < 4; ++mi)
#pragma unroll
    for (int r = 0; r < 4; ++r) {
      int row = wr * 64 + mi * 16 + q * 4 + r;
      float s = 0.f, sq = 0.f;
#pragma unroll
      for (int ni = 0; ni < 2; ++ni) { float v = a2[mi][ni][r]; s += v; sq += v * v; }
#pragma unroll
      for (int off = 1; off < 16; off <<= 1) { s += __shfl_xor(s, off); sq += __shfl_xor(sq, off); }
      if (l15 == 0) { redA[row * 4 + wc] = s; redB[row * 4 + wc] = sq; }
    }
  __syncthreads();
  if (t < 128) {
    float s  = redA[t * 4] + redA[t * 4 + 1] + redA[t * 4 + 2] + redA[t * 4 + 3];
    float sq = redB[t * 4] + redB[t * 4 + 1] + redB[t * 4 + 2] + redB[t * 4 + 3];
    float mean = s * (1.0f / 128.0f);
    float var = sq * (1.0f / 128.0f) - mean * mean;
    meanv[t] = mean; rstdv[t] = rsqrtf(var + 1e-5f);
  }
  __syncthreads();
  // LN + relu + dot(wq3)
#pragma unroll
  for (int mi = 0; mi < 4; ++mi)
#pragma unroll
    for (int r = 0; r < 4; ++r) {
      int row = wr * 64 + mi * 16 + q * 4 + r;
      float pr = 0.f;
#pragma unroll
      for (int ni = 0; ni < 2; ++ni) {
        int col = wc * 32 + ni * 16 + l15;
        float y = (a2[mi][ni][r] - meanv[row]) * rstdv[row] * ln2g[col] + ln2b[col];
        y = fmaxf(y, 0.f);
        pr += y * wq3[col];
      }
#pragma unroll
      for (int off = 1; off < 16; off <<= 1) pr += __shfl_xor(pr, off);
      if (l15 == 0) redA[row * 4 + wc] = pr;
    }
  __syncthreads();
  if (t < 128)
    out[m0 + t] = redA[t * 4] + redA[t * 4 + 1] + redA[t * 4 + 2] + redA[t * 4 + 3] + bq3[0];
}

// ---------------- launcher ----------------
extern "C" void kernel_launch(void* const* d_in, const int* in_sizes, int n_in,
                              void* d_out, int out_size, void* d_ws, size_t ws_size,
                              hipStream_t stream) {
  const float* state  = (const float*)d_in[0];
  const float* action = (const float*)d_in[1];
  const float* W1  = (const float*)d_in[2];
  const float* b1  = (const float*)d_in[3];
  const float* g1  = (const float*)d_in[4];
  const float* W2  = (const float*)d_in[5];
  const float* b2  = (const float*)d_in[6];
  const float* g2  = (const float*)d_in[7];
  const float* Wq1 = (const float*)d_in[8];
  const float* bq1 = (const float*)d_in[9];
  const float* ln1g = (const float*)d_in[10];
  const float* ln1b = (const float*)d_in[11];
  const float* Wq2 = (const float*)d_in[12];
  const float* bq2 = (const float*)d_in[13];
  const float* ln2g = (const float*)d_in[14];
  const float* ln2b = (const float*)d_in[15];
  const float* Wq3 = (const float*)d_in[16];
  const float* bq3 = (const float*)d_in[17];
  int B = in_sizes[0] / 24;

  char* ws = (char*)d_ws;
  _Float16* V1t = (_Float16*)(ws);
  _Float16* V2p = (_Float16*)(ws + 65536);
  _Float16* T1p = (_Float16*)(ws + 65536 + 2097152);
  _Float16* T2p = (_Float16*)(ws + 65536 + 2097152 + 524288);
  size_t woff = (65536 + 2097152 + 524288 + 65536 + 4095) & ~(size_t)4095;

  size_t avail = ws_size > woff ? ws_size - woff : 0;
  int S, G;
  if (avail >= (size_t)32768 * 2048 * 3) {
    S = 32768; G = 2;
  } else {
    long rows = (long)(avail / 4096);
    if (rows > 32768) rows = 32768;
    rows &= ~127L;
    if (rows < 128) rows = 128;
    S = (int)rows; G = 1;
  }
  _Float16* x1 = (_Float16*)(ws + woff);
  _Float16* x2 = x1 + (size_t)S * 1024;

  prep_weights<<<2656, 256, 0, stream>>>(W1, W2, Wq1, Wq2, V1t, V2p, T1p, T2p);

  int nsl = (B + S - 1) / S;
  for (int i = 0; i < nsl; ++i) {
    int r0 = i * S;
    int Sc = S < (B - r0) ? S : (B - r0);
    int nbm = Sc / 128;
    k1_ripple1<<<dim3(8, nbm), 256, 0, stream>>>(state, action, V1t, b1, g1, x1, r0);
    k2_ripple2<<<dim3(8 * nbm), 256, 0, stream>>>(x1, V2p, b2, g2,
                                                  x2 + (size_t)(i % G) * S * 1024, nbm);
    if (i % G == G - 1 || i == nsl - 1) {
      int gstart = (i - i % G) * S;
      int nrows = r0 + Sc - gstart;
      k3_head<<<dim3(nrows / 128), 512, 0, stream>>>(x2, T1p, T2p, bq1, ln1g, ln1b,
                                                     bq2, ln2g, ln2b, Wq3, bq3,
                                                     (float*)d_out + gstart);
    }
  }
}

// Round 7
// 622.545 us; speedup vs baseline: 1.5586x; 1.1392x over previous
//
#include <hip/hip_runtime.h>
#include <hip/hip_bf16.h>

typedef _Float16 f16x8 __attribute__((ext_vector_type(8)));
typedef _Float16 f16x4 __attribute__((ext_vector_type(4)));
typedef float f32x4 __attribute__((ext_vector_type(4)));

__device__ __forceinline__ float tanh_fast(float x) {
  float e = __expf(2.0f * x);
  return 1.0f - 2.0f * __builtin_amdgcn_rcpf(e + 1.0f);
}
__device__ __forceinline__ float sigmoid_fast(float x) {
  return __builtin_amdgcn_rcpf(1.0f + __expf(-x));
}

// ---------------- K0: weight prep ----------------
// All B operands fragment-major: tile (nt 16-cols x kt 32-k) = 512 halfwords,
// lane l elem j holds B[k=kt*32+(l>>4)*8+j][col=nt*16+(l&15)].
// V1p: tile = nt (single k-chunk). V2p/T1p/T2p: tile = nt*KT + kt.
__global__ __launch_bounds__(256) void prep_weights(
    const float* __restrict__ W1, const float* __restrict__ W2,
    const float* __restrict__ Wq1, const float* __restrict__ Wq2,
    _Float16* __restrict__ V1p, _Float16* __restrict__ V2p,
    _Float16* __restrict__ T1p, _Float16* __restrict__ T2p) {
  __shared__ float S[32 * 33];
  int b = blockIdx.x, t = threadIdx.x;
  if (b < 2624) {
    const float* in; _Float16* out; int N, nc0, tile;
    if (b < 2048) {        // W2 [32][1024][32]: h, ntl, kt
      int h = b >> 6, rem = b & 63, ntl = rem >> 5, kt = rem & 31;
      in = W2 + (size_t)h * 32768 + (size_t)kt * 32 * 32;
      N = 32; nc0 = ntl * 16;
      out = V2p; tile = (h * 2 + ntl) * 32 + kt;
    } else if (b < 2560) { // Wq1 [1024][256]
      int i = b - 2048, nt = i >> 5, kt = i & 31;
      in = Wq1 + (size_t)kt * 32 * 256; N = 256; nc0 = nt * 16;
      out = T1p; tile = nt * 32 + kt;
    } else {               // Wq2 [256][128]
      int i = b - 2560, nt = i >> 3, kt = i & 7;
      in = Wq2 + (size_t)kt * 32 * 128; N = 128; nc0 = nt * 16;
      out = T2p; tile = nt * 8 + kt;
    }
    if (t < 128) {
      int r = t >> 2, c4 = (t & 3) * 4;
      const float4 v = *(const float4*)(in + (size_t)r * N + nc0 + c4);
      S[r * 17 + c4 + 0] = v.x; S[r * 17 + c4 + 1] = v.y;
      S[r * 17 + c4 + 2] = v.z; S[r * 17 + c4 + 3] = v.w;
    }
    __syncthreads();
    if (t < 128) {
      int w2 = t >> 6, l = t & 63, q = l >> 4, l15 = l & 15;
      f16x4 o;
#pragma unroll
      for (int jj = 0; jj < 4; ++jj)
        o[jj] = (_Float16)S[(q * 8 + w2 * 4 + jj) * 17 + l15];
      *(f16x4*)(out + (size_t)tile * 512 + l * 8 + w2 * 4) = o;
    }
  } else {                 // W1 [32][32][32]: one block per head h
    int h = b - 2624;
    const float* in = W1 + h * 1024;   // [d][k_out]
    int cc = t & 31, rr8 = t >> 5;
#pragma unroll
    for (int p = 0; p < 4; ++p) {
      int r = rr8 + p * 8;
      S[cc * 33 + r] = in[r * 32 + cc];   // S[col][k] = W1[h][k][col]
    }
    __syncthreads();
    if (t < 128) {
      int ntl = t >> 6, l = t & 63, q = l >> 4, l15 = l & 15;
      f16x8 o;
#pragma unroll
      for (int j = 0; j < 8; ++j)
        o[j] = (_Float16)S[(ntl * 16 + l15) * 33 + q * 8 + j];
      *(f16x8*)(V1p + (size_t)(h * 2 + ntl) * 512 + l * 8) = o;
    }
  }
}

// ---------------- K1: ripple layer 1 ----------------
// Output x1p in fragment-major A layout.
__global__ __launch_bounds__(256) void k1_ripple1(
    const float* __restrict__ state, const float* __restrict__ action,
    const _Float16* __restrict__ v1p, const float* __restrict__ b1,
    const float* __restrict__ g1, _Float16* __restrict__ x1p, int gro) {
  __shared__ __align__(16) _Float16 SM[128 * 68];   // A-stage (stride 40) / pack (stride 68)
  int bn = blockIdx.x, bm = blockIdx.y;
  int t = threadIdx.x, w = t >> 6, l = t & 63, q = l >> 4, l15 = l & 15;
  int n0 = bn * 128, m0 = bm * 128;

  {  // stage sa tile [128][32] fp16 (concat state|action), stride 40
    int r = t >> 1, half = t & 1;
    size_t grow = (size_t)(gro + m0 + r);
    float v[16];
    if (half == 0) {
      const float4* sp = (const float4*)(state + grow * 24);
      ((float4*)v)[0] = sp[0]; ((float4*)v)[1] = sp[1];
      ((float4*)v)[2] = sp[2]; ((float4*)v)[3] = sp[3];
    } else {
      const float4* sp = (const float4*)(state + grow * 24 + 16);
      ((float4*)v)[0] = sp[0]; ((float4*)v)[1] = sp[1];
      const float4* ap = (const float4*)(action + grow * 8);
      ((float4*)v)[2] = ap[0]; ((float4*)v)[3] = ap[1];
    }
    f16x8 h0, h1;
#pragma unroll
    for (int j = 0; j < 8; ++j) { h0[j] = (_Float16)v[j]; h1[j] = (_Float16)v[8 + j]; }
    *(f16x8*)&SM[r * 40 + half * 16] = h0;
    *(f16x8*)&SM[r * 40 + half * 16 + 8] = h1;
  }
  __syncthreads();

  int wr = w >> 1, wc = w & 1;
  f16x8 af[4], bf[4];
#pragma unroll
  for (int mi = 0; mi < 4; ++mi)
    af[mi] = *(const f16x8*)&SM[(wr * 64 + mi * 16 + l15) * 40 + q * 8];
#pragma unroll
  for (int ni = 0; ni < 4; ++ni)
    bf[ni] = *(const f16x8*)(v1p + (size_t)(bn * 8 + wc * 4 + ni) * 512 + l * 8);

  f32x4 acc[4][4] = {};
#pragma unroll
  for (int mi = 0; mi < 4; ++mi)
#pragma unroll
    for (int ni = 0; ni < 4; ++ni)
      acc[mi][ni] = __builtin_amdgcn_mfma_f32_16x16x32_f16(af[mi], bf[ni], acc[mi][ni], 0, 0, 0);

  // epilogue: 2 passes of 64 contiguous cols; pack (stride 68) -> fragment-major x1p
  for (int p = 0; p < 2; ++p) {
    __syncthreads();
    if (wc == p) {
#pragma unroll
      for (int ni = 0; ni < 4; ++ni) {
        int col = n0 + p * 64 + ni * 16 + l15;
        float sg = sigmoid_fast(g1[col >> 5]);
        float bias = b1[col];
#pragma unroll
        for (int mi = 0; mi < 4; ++mi)
#pragma unroll
          for (int r = 0; r < 4; ++r) {
            int rl = wr * 64 + mi * 16 + q * 4 + r;
            SM[rl * 68 + ni * 16 + l15] = (_Float16)(tanh_fast(acc[mi][ni][r] + bias) * sg);
          }
      }
    }
    __syncthreads();
#pragma unroll
    for (int i = 0; i < 4; ++i) {
      int c = t + i * 256;
      int kcL = c >> 9, rt = (c >> 6) & 7, ll = c & 63;
      int qq = ll >> 4, ll15 = ll & 15;
      int base = (rt * 16 + ll15) * 68 + kcL * 32 + qq * 8;
      union { f16x8 v; f16x4 h[2]; } u;
      u.h[0] = *(const f16x4*)&SM[base];
      u.h[1] = *(const f16x4*)&SM[base + 4];
      *(f16x8*)(x1p + ((size_t)((m0 >> 4) + rt) * 32 + bn * 4 + p * 2 + kcL) * 512 + ll * 8) = u.v;
    }
  }
}

// ---------------- K2: ripple layer 2 (the big GEMM) ----------------
// Barrier-free streaming K-loop: A and B both fragment-major, direct
// global->register 1KB coalesced wave loads, ping-pong prefetch 1 kt ahead.
// Block 128x256 = 4 independent waves of 64x128 (acc[4][8]). No K-loop LDS.
__global__ __launch_bounds__(256, 2) void k2_ripple2(
    const _Float16* __restrict__ x1p, const _Float16* __restrict__ v2p,
    const float* __restrict__ b2, const float* __restrict__ g2,
    _Float16* __restrict__ x2p, int nbm) {
  __shared__ __align__(16) _Float16 EP[4 * 64 * 36];   // per-wave epilogue scratch (18 KB)
  int g = blockIdx.x;
  int bn, bm;
  if ((nbm & 7) == 0) {    // XCD-affine: all 4 bn of one bm on one XCD
    int x = g & 7, j = g >> 3;
    bn = j & 3; bm = x + 8 * (j >> 2);
  } else { bn = g & 3; bm = g >> 2; }
  int t = threadIdx.x, w = t >> 6, l = t & 63, q = l >> 4, l15 = l & 15;
  int wr = w >> 1, wc = w & 1;
  int rt0 = bm * 8 + wr * 4;            // 16-row tile base of this wave
  int nt0 = bn * 16 + wc * 8;           // 16-col tile base of this wave
  f32x4 acc[4][8] = {};

  const _Float16* aB = x1p + (size_t)rt0 * 16384 + l * 8;
  const _Float16* bB = v2p + (size_t)nt0 * 16384 + l * 8;

  f16x8 a0[4], b0[8], a1[4], b1v[8];
#pragma unroll
  for (int mi = 0; mi < 4; ++mi) a0[mi] = *(const f16x8*)(aB + mi * 16384);
#pragma unroll
  for (int ni = 0; ni < 8; ++ni) b0[ni] = *(const f16x8*)(bB + ni * 16384);

  for (int kt = 0; kt < 32; kt += 2) {
#pragma unroll
    for (int mi = 0; mi < 4; ++mi) a1[mi] = *(const f16x8*)(aB + mi * 16384 + (kt + 1) * 512);
#pragma unroll
    for (int ni = 0; ni < 8; ++ni) b1v[ni] = *(const f16x8*)(bB + ni * 16384 + (kt + 1) * 512);
#pragma unroll
    for (int mi = 0; mi < 4; ++mi)
#pragma unroll
      for (int ni = 0; ni < 8; ++ni)
        acc[mi][ni] = __builtin_amdgcn_mfma_f32_16x16x32_f16(a0[mi], b0[ni], acc[mi][ni], 0, 0, 0);
    if (kt + 2 < 32) {
#pragma unroll
      for (int mi = 0; mi < 4; ++mi) a0[mi] = *(const f16x8*)(aB + mi * 16384 + (kt + 2) * 512);
#pragma unroll
      for (int ni = 0; ni < 8; ++ni) b0[ni] = *(const f16x8*)(bB + ni * 16384 + (kt + 2) * 512);
    }
#pragma unroll
    for (int mi = 0; mi < 4; ++mi)
#pragma unroll
      for (int ni = 0; ni < 8; ++ni)
        acc[mi][ni] = __builtin_amdgcn_mfma_f32_16x16x32_f16(a1[mi], b1v[ni], acc[mi][ni], 0, 0, 0);
  }

  // epilogue: per-wave LDS transform C/D-layout -> fragment-major x2p.
  // 4 groups of 32 cols; stride 36 halfwords (b64 reads, ~2-way conflicts).
  _Float16* EPw = EP + w * (64 * 36);
  for (int kcg = 0; kcg < 4; ++kcg) {
#pragma unroll
    for (int np = 0; np < 2; ++np) {
      int ni = kcg * 2 + np;
      int col = (nt0 + ni) * 16 + l15;
      float sg = sigmoid_fast(g2[col >> 5]);
      float bias = b2[col];
#pragma unroll
      for (int mi = 0; mi < 4; ++mi)
#pragma unroll
        for (int r = 0; r < 4; ++r) {
          int row = mi * 16 + q * 4 + r;
          EPw[row * 36 + np * 16 + l15] = (_Float16)(tanh_fast(acc[mi][ni][r] + bias) * sg);
        }
    }
#pragma unroll
    for (int rt = 0; rt < 4; ++rt) {
      int base = (rt * 16 + l15) * 36 + q * 8;
      union { f16x8 v; f16x4 h[2]; } u;
      u.h[0] = *(const f16x4*)&EPw[base];
      u.h[1] = *(const f16x4*)&EPw[base + 4];
      *(f16x8*)(x2p + ((size_t)(rt0 + rt) * 32 + (nt0 >> 1) + kcg) * 512 + l * 8) = u.v;
    }
  }
}

// ---------------- K3: fused q-network head ----------------
// GEMM3 barrier-free streaming (A from fragment-major x2p, B from T1p),
// then LN + GEMM4 (T2p) + LN + GEMV as before. 512 threads, 2x4 waves.
__global__ __launch_bounds__(512, 3) void k3_head(
    const _Float16* __restrict__ x2p, const _Float16* __restrict__ t1p,
    const _Float16* __restrict__ t2p,
    const float* __restrict__ bq1, const float* __restrict__ ln1g, const float* __restrict__ ln1b,
    const float* __restrict__ bq2, const float* __restrict__ ln2g, const float* __restrict__ ln2b,
    const float* __restrict__ wq3, const float* __restrict__ bq3,
    float* __restrict__ out) {
  __shared__ __align__(16) _Float16 y1h[128 * 264];   // 66 KB
  __shared__ float redA[128 * 4], redB[128 * 4];
  __shared__ float meanv[128], rstdv[128];
  int bm = blockIdx.x;
  int t = threadIdx.x, w = t >> 6, l = t & 63, q = l >> 4, l15 = l & 15;
  int wr = w >> 2, wc = w & 3;   // 2 x 4 wave grid
  int qs_unused = 0; (void)qs_unused;

  // ---- GEMM3: [128 x 1024] @ [1024 x 256], streaming
  f32x4 acc[4][4] = {};
  const _Float16* aB = x2p + (size_t)(bm * 8 + wr * 4) * 16384 + l * 8;
  const _Float16* bB = t1p + (size_t)(wc * 4) * 16384 + l * 8;

  f16x8 a0[4], b0[4], a1[4], b1v[4];
#pragma unroll
  for (int mi = 0; mi < 4; ++mi) a0[mi] = *(const f16x8*)(aB + mi * 16384);
#pragma unroll
  for (int ni = 0; ni < 4; ++ni) b0[ni] = *(const f16x8*)(bB + ni * 16384);

  for (int kt = 0; kt < 32; kt += 2) {
#pragma unroll
    for (int mi = 0; mi < 4; ++mi) a1[mi] = *(const f16x8*)(aB + mi * 16384 + (kt + 1) * 512);
#pragma unroll
    for (int ni = 0; ni < 4; ++ni) b1v[ni] = *(const f16x8*)(bB + ni * 16384 + (kt + 1) * 512);
#pragma unroll
    for (int mi = 0; mi < 4; ++mi)
#pragma unroll
      for (int ni = 0; ni < 4; ++ni)
        acc[mi][ni] = __builtin_amdgcn_mfma_f32_16x16x32_f16(a0[mi], b0[ni], acc[mi][ni], 0, 0, 0);
    if (kt + 2 < 32) {
#pragma unroll
      for (int mi = 0; mi < 4; ++mi) a0[mi] = *(const f16x8*)(aB + mi * 16384 + (kt + 2) * 512);
#pragma unroll
      for (int ni = 0; ni < 4; ++ni) b0[ni] = *(const f16x8*)(bB + ni * 16384 + (kt + 2) * 512);
    }
#pragma unroll
    for (int mi = 0; mi < 4; ++mi)
#pragma unroll
      for (int ni = 0; ni < 4; ++ni)
        acc[mi][ni] = __builtin_amdgcn_mfma_f32_16x16x32_f16(a1[mi], b1v[ni], acc[mi][ni], 0, 0, 0);
  }

  // bias + row-sum/sumsq over 256 cols
#pragma unroll
  for (int ni = 0; ni < 4; ++ni) {
    int col = wc * 64 + ni * 16 + l15;
    float b = bq1[col];
#pragma unroll
    for (int mi = 0; mi < 4; ++mi)
#pragma unroll
      for (int r = 0; r < 4; ++r) acc[mi][ni][r] += b;
  }
#pragma unroll
  for (int mi = 0; mi < 4; ++mi)
#pragma unroll
    for (int r = 0; r < 4; ++r) {
      int row = wr * 64 + mi * 16 + q * 4 + r;
      float s = 0.f, sq = 0.f;
#pragma unroll
      for (int ni = 0; ni < 4; ++ni) { float v = acc[mi][ni][r]; s += v; sq += v * v; }
#pragma unroll
      for (int off = 1; off < 16; off <<= 1) { s += __shfl_xor(s, off); sq += __shfl_xor(sq, off); }
      if (l15 == 0) { redA[row * 4 + wc] = s; redB[row * 4 + wc] = sq; }
    }
  __syncthreads();
  if (t < 128) {
    float s  = redA[t * 4] + redA[t * 4 + 1] + redA[t * 4 + 2] + redA[t * 4 + 3];
    float sq = redB[t * 4] + redB[t * 4 + 1] + redB[t * 4 + 2] + redB[t * 4 + 3];
    float mean = s * (1.0f / 256.0f);
    float var = sq * (1.0f / 256.0f) - mean * mean;
    meanv[t] = mean; rstdv[t] = rsqrtf(var + 1e-5f);
  }
  __syncthreads();
  // LN + relu -> y1h
#pragma unroll
  for (int mi = 0; mi < 4; ++mi)
#pragma unroll
    for (int ni = 0; ni < 4; ++ni)
#pragma unroll
      for (int r = 0; r < 4; ++r) {
        int row = wr * 64 + mi * 16 + q * 4 + r;
        int col = wc * 64 + ni * 16 + l15;
        float y = (acc[mi][ni][r] - meanv[row]) * rstdv[row] * ln1g[col] + ln1b[col];
        y = fmaxf(y, 0.f);
        y1h[row * 264 + col] = (_Float16)y;
      }
  __syncthreads();

  // ---- GEMM4: [128 x 256] @ [256 x 128]; waves 2(row x64) x 4(col x32)
  f32x4 a2[4][2] = {};
  for (int kt = 0; kt < 8; ++kt) {
    f16x8 af2[4];
#pragma unroll
    for (int mi = 0; mi < 4; ++mi)
      af2[mi] = *(const f16x8*)&y1h[(wr * 64 + mi * 16 + l15) * 264 + kt * 32 + q * 8];
#pragma unroll
    for (int ni = 0; ni < 2; ++ni) {
      f16x8 bf = *(const f16x8*)(t2p + (size_t)(wc * 2 + ni) * 4096 + kt * 512 + l * 8);
#pragma unroll
      for (int mi = 0; mi < 4; ++mi)
        a2[mi][ni] = __builtin_amdgcn_mfma_f32_16x16x32_f16(af2[mi], bf, a2[mi][ni], 0, 0, 0);
    }
  }
#pragma unroll
  for (int ni = 0; ni < 2; ++ni) {
    int col = wc * 32 + ni * 16 + l15;
    float b = bq2[col];
#pragma unroll
    for (int mi = 0; mi < 4; ++mi)
#pragma unroll
      for (int r = 0; r < 4; ++r) a2[mi][ni][r] += b;
  }
  __syncthreads();   // redA/redB reuse
#pragma unroll
  for (int mi = 0; mi < 4; ++mi)
#pragma unroll
    for (int r = 0; r < 4; ++r) {
      int row = wr * 64 + mi * 16 + q * 4 + r;
      float s = 0.f, sq = 0.f;
#pragma unroll
      for (int ni = 0; ni < 2; ++ni) { float v = a2[mi][ni][r]; s += v; sq += v * v; }
#pragma unroll
      for (int off = 1; off < 16; off <<= 1) { s += __shfl_xor(s, off); sq += __shfl_xor(sq, off); }
      if (l15 == 0) { redA[row * 4 + wc] = s; redB[row * 4 + wc] = sq; }
    }
  __syncthreads();
  if (t < 128) {
    float s  = redA[t * 4] + redA[t * 4 + 1] + redA[t * 4 + 2] + redA[t * 4 + 3];
    float sq = redB[t * 4] + redB[t * 4 + 1] + redB[t * 4 + 2] + redB[t * 4 + 3];
    float mean = s * (1.0f / 128.0f);
    float var = sq * (1.0f / 128.0f) - mean * mean;
    meanv[t] = mean; rstdv[t] = rsqrtf(var + 1e-5f);
  }
  __syncthreads();
  // LN + relu + dot(wq3)
#pragma unroll
  for (int mi = 0; mi < 4; ++mi)
#pragma unroll
    for (int r = 0; r < 4; ++r) {
      int row = wr * 64 + mi * 16 + q * 4 + r;
      float pr = 0.f;
#pragma unroll
      for (int ni = 0; ni < 2; ++ni) {
        int col = wc * 32 + ni * 16 + l15;
        float y = (a2[mi][ni][r] - meanv[row]) * rstdv[row] * ln2g[col] + ln2b[col];
        y = fmaxf(y, 0.f);
        pr += y * wq3[col];
      }
#pragma unroll
      for (int off = 1; off < 16; off <<= 1) pr += __shfl_xor(pr, off);
      if (l15 == 0) redA[row * 4 + wc] = pr;
    }
  __syncthreads();
  if (t < 128)
    out[bm * 128 + t] = redA[t * 4] + redA[t * 4 + 1] + redA[t * 4 + 2] + redA[t * 4 + 3] + bq3[0];
}

// ---------------- launcher ----------------
extern "C" void kernel_launch(void* const* d_in, const int* in_sizes, int n_in,
                              void* d_out, int out_size, void* d_ws, size_t ws_size,
                              hipStream_t stream) {
  const float* state  = (const float*)d_in[0];
  const float* action = (const float*)d_in[1];
  const float* W1  = (const float*)d_in[2];
  const float* b1  = (const float*)d_in[3];
  const float* g1  = (const float*)d_in[4];
  const float* W2  = (const float*)d_in[5];
  const float* b2  = (const float*)d_in[6];
  const float* g2  = (const float*)d_in[7];
  const float* Wq1 = (const float*)d_in[8];
  const float* bq1 = (const float*)d_in[9];
  const float* ln1g = (const float*)d_in[10];
  const float* ln1b = (const float*)d_in[11];
  const float* Wq2 = (const float*)d_in[12];
  const float* bq2 = (const float*)d_in[13];
  const float* ln2g = (const float*)d_in[14];
  const float* ln2b = (const float*)d_in[15];
  const float* Wq3 = (const float*)d_in[16];
  const float* bq3 = (const float*)d_in[17];
  int B = in_sizes[0] / 24;

  char* ws = (char*)d_ws;
  _Float16* V1p = (_Float16*)(ws);
  _Float16* V2p = (_Float16*)(ws + 65536);
  _Float16* T1p = (_Float16*)(ws + 65536 + 2097152);
  _Float16* T2p = (_Float16*)(ws + 65536 + 2097152 + 524288);
  size_t woff = (65536 + 2097152 + 524288 + 65536 + 4095) & ~(size_t)4095;

  size_t avail = ws_size > woff ? ws_size - woff : 0;
  int S, G;
  if (avail >= (size_t)32768 * 2048 * 3) {
    S = 32768; G = 2;
  } else {
    long rows = (long)(avail / 4096);
    if (rows > 32768) rows = 32768;
    rows &= ~127L;
    if (rows < 128) rows = 128;
    S = (int)rows; G = 1;
  }
  _Float16* x1 = (_Float16*)(ws + woff);
  _Float16* x2 = x1 + (size_t)S * 1024;

  prep_weights<<<2656, 256, 0, stream>>>(W1, W2, Wq1, Wq2, V1p, V2p, T1p, T2p);

  int nsl = (B + S - 1) / S;
  for (int i = 0; i < nsl; ++i) {
    int r0 = i * S;
    int Sc = S < (B - r0) ? S : (B - r0);
    int nbm = Sc / 128;
    k1_ripple1<<<dim3(8, nbm), 256, 0, stream>>>(state, action, V1p, b1, g1, x1, r0);
    k2_ripple2<<<dim3(4 * nbm), 256, 0, stream>>>(x1, V2p, b2, g2,
                                                  x2 + (size_t)(i % G) * S * 1024, nbm);
    if (i % G == G - 1 || i == nsl - 1) {
      int gstart = (i - i % G) * S;
      int nrows = r0 + Sc - gstart;
      k3_head<<<dim3(nrows / 128), 512, 0, stream>>>(x2, T1p, T2p, bq1, ln1g, ln1b,
                                                     bq2, ln2g, ln2b, Wq3, bq3,
                                                     (float*)d_out + gstart);
    }
  }
}